// Round 2
// baseline (254.309 us; speedup 1.0000x reference)
//
#include <hip/hip_runtime.h>
#include <cmath>

#define N_NODES 30460
#define D 64
#define B 128
#define K_SEL 6924
#define S_TOT (B * K_SEL)      /* 886272 */
#define M_TOT (B * 50)         /* 6400 */
#define A_HID 20

// workspace layout (in floats)
#define WS_EXPB  0
#define WS_DENOM (WS_EXPB + M_TOT)      /* 6400  : [B] */
#define WS_ACC   (WS_DENOM + B)         /* 6528  : [B*D] */
#define WS_PORT  (WS_ACC + B * D)       /* 14720 : [B*D] */
#define WS_TW    (WS_PORT + B * D)      /* 22912 : [2*B] */

// ---- portrait stage 1: beta -> exp(beta) per mention; also zeroes acc/denom ----
__global__ __launch_bounds__(256) void k_beta(
    const float* __restrict__ graph, const float* __restrict__ Wa,
    const float* __restrict__ Va, const int* __restrict__ midx,
    float* __restrict__ ws) {
    __shared__ float sWa[D * A_HID];
    __shared__ float sVa[A_HID];
    int t = threadIdx.x;
    for (int i = t; i < D * A_HID; i += 256) sWa[i] = Wa[i];
    if (t < A_HID) sVa[t] = Va[t];
    int m = blockIdx.x * 256 + t;
    // zero denom+acc (contiguous, B + B*D = 8320 floats) — harness poisons ws
    if (m < B + B * D) ws[WS_DENOM + m] = 0.f;
    __syncthreads();
    if (m >= M_TOT) return;
    int idx = midx[m];
    const float* me = graph + (size_t)idx * D;
    float h[A_HID];
#pragma unroll
    for (int j = 0; j < A_HID; j++) h[j] = 0.f;
    for (int d = 0; d < D; d++) {
        float v = me[d];
#pragma unroll
        for (int j = 0; j < A_HID; j++) h[j] += v * sWa[d * A_HID + j];
    }
    float beta = 0.f;
#pragma unroll
    for (int j = 0; j < A_HID; j++) beta += tanhf(h[j]) * sVa[j];
    ws[WS_EXPB + m] = expf(beta);
}

// ---- portrait stage 2: atomic segment-sum of exp*me and exp ----
__global__ __launch_bounds__(256) void k_scatter(
    const float* __restrict__ graph, const int* __restrict__ midx,
    const int* __restrict__ mbat, float* __restrict__ ws) {
    const float* expb = ws + WS_EXPB;
    float* denom = ws + WS_DENOM;
    float* acc = ws + WS_ACC;
    int tid = blockIdx.x * 256 + threadIdx.x;
    int m = tid >> 6, d = tid & 63;
    if (m >= M_TOT) return;
    float e = expb[m];
    int b = mbat[m];
    float v = graph[(size_t)midx[m] * D + d];
    atomicAdd(&acc[b * D + d], e * v);
    if (d == 0) atomicAdd(&denom[b], e);
}

// ---- fused: normalize portrait + per-group gate tw (one wave per (l,g)) ----
__global__ __launch_bounds__(256) void k_twport(
    const float* __restrict__ graph, const float* __restrict__ abs_e,
    const float* __restrict__ utter,
    const float* __restrict__ W1w, const float* __restrict__ W1b,
    const float* __restrict__ W2w, const float* __restrict__ W2b,
    const int* __restrict__ gb0, const int* __restrict__ la0, const int* __restrict__ it0,
    const int* __restrict__ gb1, const int* __restrict__ la1, const int* __restrict__ it1,
    float* __restrict__ ws) {
    const float* denom = ws + WS_DENOM;
    const float* acc   = ws + WS_ACC;
    int gt = blockIdx.x * 256 + threadIdx.x;   // 0..16383 (64 blocks)
    // phase A: write normalized portrait for k_score
    if (gt < B * D) ws[WS_PORT + gt] = acc[gt] / denom[gt >> 6];
    // phase B: one wave per (layer, group); reads acc/denom directly (no dependency on phase A)
    int w = gt >> 6;                 // 0..255
    int lane = gt & 63;
    int l = w >> 7, g = w & (B - 1);
    const int* gbp = l ? gb1 : gb0;
    const int* lap = l ? la1 : la0;
    const int* itp = l ? it1 : it0;
    const float* Ww = l ? W2w : W1w;
    const float* Wb = l ? W2b : W1b;
    int gb = gbp[g], li = lap[g], it = itp[g];
    const float* wr = Ww + it * 3 * D;
    float rd = 1.f / denom[gb];
    float u = utter[(size_t)gb * D + lane];
    float p = acc[(size_t)gb * D + lane] * rd;
    float sv = (li < N_NODES) ? graph[(size_t)li * D + lane] : abs_e[lane];
    float a = wr[lane] * u + wr[D + lane] * p + wr[2 * D + lane] * sv;
    a += __shfl_xor(a, 32, 64);
    a += __shfl_xor(a, 16, 64);
    a += __shfl_xor(a, 8, 64);
    a += __shfl_xor(a, 4, 64);
    a += __shfl_xor(a, 2, 64);
    a += __shfl_xor(a, 1, 64);
    if (lane == 0) ws[WS_TW + l * B + g] = 1.f / (1.f + expf(-(a + Wb[it])));
}

// ---- main scoring: one output per lane, split-dot blend ----
__global__ __launch_bounds__(256) void k_score(
    const float* __restrict__ graph, const float* __restrict__ abs_e,
    const float* __restrict__ utter, const float* __restrict__ ws,
    const int* __restrict__ si0, const int* __restrict__ sb0, const int* __restrict__ sg0,
    const int* __restrict__ si1, const int* __restrict__ sb1, const int* __restrict__ sg1,
    float* __restrict__ out) {
    const float* port = ws + WS_PORT;
    const float* tws  = ws + WS_TW;
    const int layer = blockIdx.y;
    const int* __restrict__ si = layer ? si1 : si0;
    const int* __restrict__ sb = layer ? sb1 : sb0;
    const int* __restrict__ sg = layer ? sg1 : sg0;
    int s = blockIdx.x * 256 + threadIdx.x;    // S_TOT = 3462 * 256 exactly

    int idx = si[s];
    int bat = sb[s];
    int grp = sg[s];
    float tw = tws[layer * B + grp];

    const float4* __restrict__ row = (const float4*)((idx < N_NODES) ? (graph + (size_t)idx * D) : abs_e);
    const float4* __restrict__ u4  = (const float4*)(utter + (size_t)bat * D);
    const float4* __restrict__ p4  = (const float4*)(port + (size_t)bat * D);

    float du0 = 0.f, du1 = 0.f, dp0 = 0.f, dp1 = 0.f;
#pragma unroll 4
    for (int k = 0; k < 16; k += 2) {
        float4 ga = row[k],     gbv = row[k + 1];
        float4 ua = u4[k],      ub  = u4[k + 1];
        float4 pa = p4[k],      pb  = p4[k + 1];
        du0 += ga.x * ua.x + ga.y * ua.y + ga.z * ua.z + ga.w * ua.w;
        du1 += gbv.x * ub.x + gbv.y * ub.y + gbv.z * ub.z + gbv.w * ub.w;
        dp0 += ga.x * pa.x + ga.y * pa.y + ga.z * pa.z + ga.w * pa.w;
        dp1 += gbv.x * pb.x + gbv.y * pb.y + gbv.z * pb.z + gbv.w * pb.w;
    }
    out[(size_t)layer * S_TOT + s] = tw * (du0 + du1) + (1.f - tw) * (dp0 + dp1);
}

extern "C" void kernel_launch(void* const* d_in, const int* in_sizes, int n_in,
                              void* d_out, int out_size, void* d_ws, size_t ws_size,
                              hipStream_t stream) {
    const float* graph = (const float*)d_in[0];
    const float* utter = (const float*)d_in[1];
    const float* abs_e = (const float*)d_in[2];
    const float* Wa    = (const float*)d_in[3];
    const float* Va    = (const float*)d_in[4];
    const float* W1w   = (const float*)d_in[5];
    const float* W1b   = (const float*)d_in[6];
    const float* W2w   = (const float*)d_in[7];
    const float* W2b   = (const float*)d_in[8];
    const int* midx = (const int*)d_in[9];
    const int* mbat = (const int*)d_in[10];
    const int* si0 = (const int*)d_in[11];
    const int* sb0 = (const int*)d_in[12];
    const int* sg0 = (const int*)d_in[13];
    const int* gb0 = (const int*)d_in[14];
    const int* la0 = (const int*)d_in[15];
    const int* it0 = (const int*)d_in[16];
    const int* si1 = (const int*)d_in[17];
    const int* sb1 = (const int*)d_in[18];
    const int* sg1 = (const int*)d_in[19];
    const int* gb1 = (const int*)d_in[20];
    const int* la1 = (const int*)d_in[21];
    const int* it1 = (const int*)d_in[22];

    float* ws = (float*)d_ws;

    // k_beta also zeroes denom+acc (8320 floats) → grid must cover 8320 threads
    k_beta<<<33, 256, 0, stream>>>(graph, Wa, Va, midx, ws);
    k_scatter<<<(M_TOT * 64) / 256, 256, 0, stream>>>(graph, midx, mbat, ws);
    k_twport<<<64, 256, 0, stream>>>(graph, abs_e, utter, W1w, W1b, W2w, W2b,
                                     gb0, la0, it0, gb1, la1, it1, ws);

    dim3 grid(S_TOT / 256, 2);   // 3462 x 2
    k_score<<<grid, 256, 0, stream>>>(graph, abs_e, utter, ws,
                                      si0, sb0, sg0, si1, sb1, sg1, (float*)d_out);
}

// Round 3
// 192.164 us; speedup vs baseline: 1.3234x; 1.3234x over previous
//
#include <hip/hip_runtime.h>
#include <cmath>

#define N_NODES 30460
#define D 64
#define B 128
#define K_SEL 6924
#define S_TOT (B * K_SEL)      /* 886272 */
#define NPAD 30464             /* 30461 rounded to x64; rows >30460 never read */

// ws layout (floats): port [B*D] | tw [2*B] | table [B*NPAD*2]  (~31.3 MB total)
#define WS_PORT 0
#define WS_TW   (B * D)
#define WS_TAB  (B * D + 2 * B)

// ---- portrait: one 64-thread block per batch; no global atomics ----
__global__ __launch_bounds__(64) void k_portrait(
    const float* __restrict__ graph, const float* __restrict__ Wa,
    const float* __restrict__ Va, const int* __restrict__ midx,
    float* __restrict__ port) {
    __shared__ float sWa[D * 20];
    __shared__ float sVa[20];
    __shared__ float sExp[64];
    __shared__ int   sIdx[64];
    int b = blockIdx.x, t = threadIdx.x;
    for (int i = t; i < D * 20; i += 64) sWa[i] = Wa[i];
    if (t < 20) sVa[t] = Va[t];
    __syncthreads();

    float e = 0.f; int mi = 0;
    if (t < 50) {
        mi = midx[b * 50 + t];
        const float* me = graph + (size_t)mi * D;
        float h[20];
#pragma unroll
        for (int j = 0; j < 20; j++) h[j] = 0.f;
        for (int d = 0; d < D; d++) {
            float v = me[d];
#pragma unroll
            for (int j = 0; j < 20; j++) h[j] += v * sWa[d * 20 + j];
        }
        float beta = 0.f;
#pragma unroll
        for (int j = 0; j < 20; j++) beta += tanhf(h[j]) * sVa[j];
        e = expf(beta);
    }
    sExp[t] = e;
    sIdx[t] = mi;
    __syncthreads();

    // denom = sum of 64 slots (lanes >=50 contribute 0)
    float x = sExp[t];
    x += __shfl_xor(x, 32, 64); x += __shfl_xor(x, 16, 64);
    x += __shfl_xor(x, 8, 64);  x += __shfl_xor(x, 4, 64);
    x += __shfl_xor(x, 2, 64);  x += __shfl_xor(x, 1, 64);

    // port[b][t] = sum_m exp_m * me[m][t] / denom   (lane t = d)
    float acc = 0.f;
#pragma unroll 10
    for (int m = 0; m < 50; m++)
        acc += sExp[m] * graph[(size_t)sIdx[m] * D + t];
    port[b * D + t] = acc / x;
}

// ---- table: U[b,n]=utter[b].ge[n], P[b,n]=port[b].ge[n]; wave0 side-task: tw ----
__global__ __launch_bounds__(256) void k_table(
    const float* __restrict__ graph, const float* __restrict__ abs_e,
    const float* __restrict__ utter, const float* __restrict__ port,
    const float* __restrict__ W1w, const float* __restrict__ W1b,
    const float* __restrict__ W2w, const float* __restrict__ W2b,
    const int* __restrict__ gb0, const int* __restrict__ la0, const int* __restrict__ it0,
    const int* __restrict__ gb1, const int* __restrict__ la1, const int* __restrict__ it1,
    float* __restrict__ tws, float2* __restrict__ tab) {
    // side task: blocks 0..255, wave 0 computes tw for (l,g)
    if (blockIdx.x < 2 * B && threadIdx.x < 64) {
        int l = blockIdx.x >> 7, g = blockIdx.x & (B - 1), lane = threadIdx.x;
        const int* gbp = l ? gb1 : gb0;
        const int* lap = l ? la1 : la0;
        const int* itp = l ? it1 : it0;
        const float* Ww = l ? W2w : W1w;
        const float* Wb = l ? W2b : W1b;
        int gb = gbp[g], li = lap[g], it = itp[g];
        const float* wr = Ww + it * 3 * D;
        float u = utter[(size_t)gb * D + lane];
        float p = port[(size_t)gb * D + lane];
        float sv = (li < N_NODES) ? graph[(size_t)li * D + lane] : abs_e[lane];
        float a = wr[lane] * u + wr[D + lane] * p + wr[2 * D + lane] * sv;
        a += __shfl_xor(a, 32, 64); a += __shfl_xor(a, 16, 64);
        a += __shfl_xor(a, 8, 64);  a += __shfl_xor(a, 4, 64);
        a += __shfl_xor(a, 2, 64);  a += __shfl_xor(a, 1, 64);
        if (lane == 0) tws[l * B + g] = 1.f / (1.f + expf(-(a + Wb[it])));
    }

    // main: grid.x = 119*4; nb picks 256 n's, bc picks 32 b's
    int nb = blockIdx.x >> 2, bc = blockIdx.x & 3;
    int n = nb * 256 + threadIdx.x;
    if (n > N_NODES) return;
    const float4* grow = (const float4*)((n < N_NODES) ? (graph + (size_t)n * D) : abs_e);
    float4 g4[16];
#pragma unroll
    for (int k = 0; k < 16; k++) g4[k] = grow[k];

    int b0 = bc * 32;
    for (int b = b0; b < b0 + 32; ++b) {
        const float* ub = utter + (size_t)b * D;
        const float* pb = port + (size_t)b * D;
        float du = 0.f, dp = 0.f;
#pragma unroll
        for (int k = 0; k < 16; k++) {
            float4 gv = g4[k];
            du += gv.x * ub[4*k] + gv.y * ub[4*k+1] + gv.z * ub[4*k+2] + gv.w * ub[4*k+3];
            dp += gv.x * pb[4*k] + gv.y * pb[4*k+1] + gv.z * pb[4*k+2] + gv.w * pb[4*k+3];
        }
        tab[(size_t)b * NPAD + n] = make_float2(du, dp);
    }
}

// ---- scoring: one 8B gather + 1 FMA per output ----
__global__ __launch_bounds__(256) void k_out(
    const int* __restrict__ si0, const int* __restrict__ si1,
    const float* __restrict__ tws, const float2* __restrict__ tab,
    float* __restrict__ out) {
    int layer = blockIdx.y;
    const int* __restrict__ si = layer ? si1 : si0;
    int s = blockIdx.x * 256 + threadIdx.x;
    int idx = si[s];
    unsigned bat = (unsigned)s / (unsigned)K_SEL;   // sel_batch/group_index = repeat(arange(B),K)
    float tw = tws[layer * B + bat];
    float2 v = tab[(size_t)bat * NPAD + idx];
    out[(size_t)layer * S_TOT + s] = v.y + tw * (v.x - v.y);
}

extern "C" void kernel_launch(void* const* d_in, const int* in_sizes, int n_in,
                              void* d_out, int out_size, void* d_ws, size_t ws_size,
                              hipStream_t stream) {
    const float* graph = (const float*)d_in[0];
    const float* utter = (const float*)d_in[1];
    const float* abs_e = (const float*)d_in[2];
    const float* Wa    = (const float*)d_in[3];
    const float* Va    = (const float*)d_in[4];
    const float* W1w   = (const float*)d_in[5];
    const float* W1b   = (const float*)d_in[6];
    const float* W2w   = (const float*)d_in[7];
    const float* W2b   = (const float*)d_in[8];
    const int* midx = (const int*)d_in[9];
    const int* si0 = (const int*)d_in[11];
    const int* gb0 = (const int*)d_in[14];
    const int* la0 = (const int*)d_in[15];
    const int* it0 = (const int*)d_in[16];
    const int* si1 = (const int*)d_in[17];
    const int* gb1 = (const int*)d_in[20];
    const int* la1 = (const int*)d_in[21];
    const int* it1 = (const int*)d_in[22];

    float* ws   = (float*)d_ws;
    float* port = ws + WS_PORT;
    float* tws  = ws + WS_TW;
    float2* tab = (float2*)(ws + WS_TAB);

    k_portrait<<<B, 64, 0, stream>>>(graph, Wa, Va, midx, port);

    k_table<<<119 * 4, 256, 0, stream>>>(graph, abs_e, utter, port,
                                         W1w, W1b, W2w, W2b,
                                         gb0, la0, it0, gb1, la1, it1,
                                         tws, tab);

    dim3 grid(S_TOT / 256, 2);   // 3462 x 2
    k_out<<<grid, 256, 0, stream>>>(si0, si1, tws, tab, (float*)d_out);
}